// Round 4
// baseline (93.051 us; speedup 1.0000x reference)
//
#include <hip/hip_runtime.h>

#define NG 512
#define NPX 262144
#define BLOCK 256
#define GTILE 8          // Gaussians per scalar-load tile
#define CPG 6            // coeffs per Gaussian: p00, p01, nu, p11, nv, l2a

typedef float v2f __attribute__((ext_vector_type(2)));

#if __has_builtin(__builtin_amdgcn_exp2f)
  #define KSCALE 0.72134752044448170368f   /* 0.5 * log2(e) */
  #define EXP2F(w) __builtin_amdgcn_exp2f(w)
#else
  #define KSCALE 0.72134752044448170368f
  #define EXP2F(w) exp2f(w)
#endif

// Kernel 1: per-Gaussian coefficient precompute into d_ws.
//   t(pixel) = l2a - u^2 - v^2,  u = p00*x + p01*y + nu,  v = p11*y + nv
//   result = sum 2^t   (alpha and the 0.5*log2e scale folded in)
__global__ __launch_bounds__(256)
void gsplat_prep(const float* __restrict__ alphas,
                 const float* __restrict__ means,
                 const float* __restrict__ rotations,
                 const float* __restrict__ scales,
                 float* __restrict__ cp)
{
    int n = blockIdx.x * 256 + threadIdx.x;
    if (n >= NG) return;
    float rot = rotations[n];
    float sth, cth;
    sincosf(rot, &sth, &cth);
    float s0 = scales[2 * n + 0];
    float s1 = scales[2 * n + 1];
    // RS = [[s0*c, -s1*s], [s0*s, s1*c]], RSSR = RS*RS^T, cov = inv(RSSR)
    float r00 = s0 * cth, r01 = -s1 * sth;
    float r10 = s0 * sth, r11 =  s1 * cth;
    float Ar = r00 * r00 + r01 * r01;
    float Br = r00 * r10 + r01 * r11;
    float Dr = r10 * r10 + r11 * r11;
    float det = Ar * Dr - Br * Br;
    float kc00 =  KSCALE * Dr / det;
    float kc01 = -KSCALE * Br / det;
    // Cholesky of scaled cov: k*q = (p00*dx + p01*dy)^2 + (p11*dy)^2
    float p00 = sqrtf(kc00);
    float p01 = kc01 / p00;
    float p11 = sqrtf(KSCALE / Dr);   // exact: kc11 - kc01^2/kc00 = KSCALE/Dr
    float mx = means[2 * n + 0];
    float my = means[2 * n + 1];
    cp[n * CPG + 0] = p00;
    cp[n * CPG + 1] = p01;
    cp[n * CPG + 2] = -(p00 * mx + p01 * my);
    cp[n * CPG + 3] = p11;
    cp[n * CPG + 4] = -(p11 * my);
    cp[n * CPG + 5] = log2f(alphas[n]);   // alpha==0 -> -inf -> exp2 -> 0, correct
}

// Kernel 2: main splat. Params come in via wave-uniform scalar loads (sK$),
// zero LDS. Two pixels per thread as float2 SIMD to enable v_pk_*_f32.
__global__ __launch_bounds__(BLOCK, 2)
void gsplat_kernel(const float* __restrict__ x,
                   const float* __restrict__ cp,
                   float* __restrict__ out)
{
    int tid = blockIdx.x * BLOCK + threadIdx.x;
    float4 xv = ((const float4*)x)[tid];   // 2 pixels' (x,y)
    v2f X = { xv.x, xv.z };
    v2f Y = { xv.y, xv.w };

    v2f acc = { 0.0f, 0.0f };
    for (int t = 0; t < NG; t += GTILE) {
        // contiguous 48-dword run at a loop-uniform address -> s_load_dwordx16
        float c[GTILE * CPG];
        #pragma unroll
        for (int j = 0; j < GTILE * CPG; ++j)
            c[j] = cp[t * CPG + j];

        #pragma unroll
        for (int j = 0; j < GTILE; ++j) {
            const float* g = &c[j * CPG];
            v2f u = g[0] * X + g[1] * Y + g[2];
            v2f v = g[3] * Y + g[4];
            v2f w = g[5] - u * u - v * v;     // l2a - u^2 - v^2 (fma-contracted)
            v2f e = { EXP2F(w.x), EXP2F(w.y) };
            acc += e;
        }
    }

    ((float2*)out)[tid] = make_float2(acc.x, acc.y);
}

extern "C" void kernel_launch(void* const* d_in, const int* in_sizes, int n_in,
                              void* d_out, int out_size, void* d_ws, size_t ws_size,
                              hipStream_t stream) {
    const float* x         = (const float*)d_in[0];
    const float* alphas    = (const float*)d_in[1];
    const float* means     = (const float*)d_in[2];
    const float* rotations = (const float*)d_in[3];
    const float* scales    = (const float*)d_in[4];
    float* out = (float*)d_out;
    float* cp  = (float*)d_ws;    // NG*CPG floats = 12 KB

    gsplat_prep<<<(NG + 255) / 256, 256, 0, stream>>>(alphas, means, rotations, scales, cp);
    int grid = NPX / (BLOCK * 2);  // 512 blocks, 2 pixels/thread
    gsplat_kernel<<<grid, BLOCK, 0, stream>>>(x, cp, out);
}